// Round 15
// baseline (2127.795 us; speedup 1.0000x reference)
//
#include <hip/hip_runtime.h>
#include <math.h>

#define HH   64
#define NN   65536
#define EE   524288
#define GGG  256
#define OUTC 128
#define NFF  9
#define VV   128
#define DTOT (NN*HH)
#define ENC_BLOCKS (NN/64)
#define HIST_BLOCKS (EE/256)

__device__ __forceinline__ float gelu_exact(float x){
    return 0.5f * x * (1.0f + erff(x * 0.70710678118654752f));
}

// ---------------- merged setup: cayley(b0) + gbound(b1) + enc(b2..) + hist ----
// 16.6 KB static LDS for ALL roles -> 9 blocks/CU (was 48.5 KB -> 3/CU).
__global__ __launch_bounds__(256) void setup_kernel(
    const int* __restrict__ dx, const float* __restrict__ emb,
    const float* __restrict__ W1, const float* __restrict__ b1,
    const float* __restrict__ W2, const float* __restrict__ b2,
    float* __restrict__ xinj,
    const float* __restrict__ M, float* __restrict__ WcT,
    const int* __restrict__ batch, int* __restrict__ gstart,
    const int* __restrict__ ei, int* __restrict__ counts)
{
    __shared__ float smem[64*65];     // enc A-tile OR cayley in-place inverse
    int b = blockIdx.x;
    int t = threadIdx.x;
    if (b == 0){
        // ---- Cayley: in-place GJ inversion of A = I+S in [64][65] LDS.
        // Wc = 2*(I+S)^-1 - I. Thread owns col c (0..63) x rows h*16..h*16+15.
        float* A = smem;
        int c = t & 63;
        int h = t >> 6;               // 0..3
        for (int idx = t; idx < 64*64; idx += 256){
            int i = idx >> 6, j = idx & 63;
            float s = 0.5f*(M[i*HH+j] - M[j*HH+i]);
            A[i*65 + j] = ((i==j)?1.f:0.f) + s;
        }
        __syncthreads();
        for (int k=0;k<64;++k){
            float piv    = A[k*65 + k];
            float rowk_c = A[k*65 + c];
            float fc[16];
            #pragma unroll
            for (int r=0;r<16;++r) fc[r] = A[(h*16+r)*65 + k];
            __syncthreads();
            float pinv = 1.f/piv;
            float rowk_s = rowk_c * pinv;
            #pragma unroll
            for (int r=0;r<16;++r){
                int i = h*16 + r;
                float nv;
                if (i == k) nv = (c==k) ? pinv : rowk_s;
                else        nv = (c==k) ? (-fc[r]*pinv) : fmaf(-fc[r], rowk_s, A[i*65+c]);
                A[i*65+c] = nv;
            }
            __syncthreads();
        }
        // A[i][c] = Ainv[i][c]; WcT[k*64+c] = Wc[c][k] = 2*Ainv[c][k] - (k==c)
        for (int idx=t; idx<64*64; idx+=256){
            int k = idx >> 6, cc = idx & 63;
            WcT[k*HH+cc] = 2.f*A[cc*65 + k] - ((k==cc)?1.f:0.f);
        }
    } else if (b == 1){
        int g = t;
        int lo = 0, hi = NN;
        while (lo < hi){ int mid = (lo+hi)>>1; if (batch[mid] < g) lo = mid+1; else hi = mid; }
        gstart[g] = lo;
        if (g == 0) gstart[GGG] = NN;
    } else if (b < 2 + ENC_BLOCKS){
        // ---- enc: AtomEncoder + MLP, 64-node tile; W1/W2 read from global (L2)
        float* A = smem;              // [64][65]
        int lane = t & 63;
        int w = t >> 6;
        int tile0 = (b-2) * 64;
        for (int j=0;j<16;++j){
            int nl = w*16 + j;
            int n = tile0 + nl;
            float hsum = 0.f;
            #pragma unroll
            for (int f=0; f<NFF; ++f){
                int idx = dx[n*NFF+f];
                hsum += emb[(f*VV + idx)*HH + lane];
            }
            A[nl*65 + lane] = fmaxf(hsum, 0.f);
        }
        __syncthreads();
        int tn = t & 15;
        int tc = t >> 4;
        float c4[4][4];
        #pragma unroll
        for (int i=0;i<4;++i){
            #pragma unroll
            for (int j=0;j<4;++j) c4[i][j]=0.f;
        }
        #pragma unroll 4
        for (int k=0;k<64;++k){
            float4 bb = *(const float4*)&W1[k*64 + tc*4];
            #pragma unroll
            for (int i=0;i<4;++i){
                float a = A[(tn+16*i)*65 + k];
                c4[i][0] = fmaf(a, bb.x, c4[i][0]);
                c4[i][1] = fmaf(a, bb.y, c4[i][1]);
                c4[i][2] = fmaf(a, bb.z, c4[i][2]);
                c4[i][3] = fmaf(a, bb.w, c4[i][3]);
            }
        }
        float4 b1v = *(const float4*)&b1[tc*4];
        float b1a[4] = {b1v.x, b1v.y, b1v.z, b1v.w};
        __syncthreads();
        #pragma unroll
        for (int i=0;i<4;++i){
            #pragma unroll
            for (int j=0;j<4;++j)
                A[(tn+16*i)*65 + tc*4+j] = gelu_exact(c4[i][j] + b1a[j]);
        }
        __syncthreads();
        #pragma unroll
        for (int i=0;i<4;++i){
            #pragma unroll
            for (int j=0;j<4;++j) c4[i][j]=0.f;
        }
        #pragma unroll 4
        for (int k=0;k<64;++k){
            float4 bb = *(const float4*)&W2[k*64 + tc*4];
            #pragma unroll
            for (int i=0;i<4;++i){
                float a = A[(tn+16*i)*65 + k];
                c4[i][0] = fmaf(a, bb.x, c4[i][0]);
                c4[i][1] = fmaf(a, bb.y, c4[i][1]);
                c4[i][2] = fmaf(a, bb.z, c4[i][2]);
                c4[i][3] = fmaf(a, bb.w, c4[i][3]);
            }
        }
        float4 b2v = *(const float4*)&b2[tc*4];
        #pragma unroll
        for (int i=0;i<4;++i){
            int n = tile0 + tn + 16*i;
            float4 o4;
            o4.x = c4[i][0] + b2v.x;
            o4.y = c4[i][1] + b2v.y;
            o4.z = c4[i][2] + b2v.z;
            o4.w = c4[i][3] + b2v.w;
            *(float4*)&xinj[n*HH + tc*4] = o4;
        }
    } else {
        int e = (b - 2 - ENC_BLOCKS)*256 + t;
        if (e < EE) atomicAdd(&counts[ei[EE + e]], 1);
    }
}

// ---------------- CSR scan + fill ----------------
__global__ __launch_bounds__(1024) void scan_kernel(const int* __restrict__ counts, int* __restrict__ row_ptr, int* __restrict__ cursor){
    __shared__ int lds[1024];
    int t = threadIdx.x;
    int base = t*64;
    int s=0;
    for (int i=0;i<64;++i) s += counts[base+i];
    lds[t]=s; __syncthreads();
    if (t==0){ int run=0; for (int i=0;i<1024;++i){ int v=lds[i]; lds[i]=run; run+=v; } }
    __syncthreads();
    int run = lds[t];
    for (int i=0;i<64;++i){ row_ptr[base+i]=run; cursor[base+i]=run; run += counts[base+i]; }
    if (t==1023) row_ptr[NN]=run;
}

// pack: x = src | (dst&31)<<16  (src < 65536 fits 16 bits; tile = 32 nodes)
__global__ void fill_kernel(const int* __restrict__ ei, const float* __restrict__ ew,
                            int* __restrict__ cursor, int2* __restrict__ s_edge){
    int e = blockIdx.x*blockDim.x + threadIdx.x;
    if (e < EE){
        int dstn = ei[EE+e];
        int pos = atomicAdd(&cursor[dstn], 1);
        s_edge[pos] = make_int2((ei[e] & 0xFFFF) | ((dstn & 31) << 16), __float_as_int(ew[e]));
    }
}

// ---------------- f evaluations ----------------
__global__ __launch_bounds__(256) void feval0_kernel(const float* __restrict__ xinj, const float* __restrict__ cb,
                              float* __restrict__ F0, float* __restrict__ G0, float* __restrict__ gram){
    float ps = 0.f;
    int stride = gridDim.x*blockDim.x;
    for (int i = blockIdx.x*blockDim.x + threadIdx.x; i < DTOT; i += stride){
        float v = fmaxf(cb[i&63] + xinj[i], 0.f);
        F0[i]=v; G0[i]=v; ps += v*v;
    }
    #pragma unroll
    for (int off=32; off>0; off>>=1) ps += __shfl_down(ps, off, 64);
    __shared__ float red[4];
    int lane = threadIdx.x&63, w = threadIdx.x>>6;
    if (lane==0) red[w]=ps;
    __syncthreads();
    if (threadIdx.x==0) atomicAdd(&gram[0], red[0]+red[1]+red[2]+red[3]);
}

// F = relu(Wc @ agg(z) + cb + xinj). 32-node tile.
// Edge-PARALLEL gather: block's CSR range split contiguously over 4 waves;
// 8 independent z-row loads + 8 LDS float atomicAdds per iteration (no chains).
template<int NOTH, int FINAL>
__global__ __launch_bounds__(256) void feval_kernel(
    const float* __restrict__ z, const float* __restrict__ xinj,
    const float* __restrict__ WcT, const float* __restrict__ cb,
    const int* __restrict__ row_ptr, const int2* __restrict__ s_edge,
    float* __restrict__ Fo, float* __restrict__ Go,
    const float* __restrict__ Gbase, float* __restrict__ gram, int newSlot, int4 oth,
    float* __restrict__ bn1, float* __restrict__ bn2)
{
    __shared__ float A[32*65];
    int t = threadIdx.x;
    const float* gop[4];
    {
        int o4[4] = {oth.x, oth.y, oth.z, oth.w};
        #pragma unroll
        for (int o=0;o<4;++o) gop[o] = Gbase + (size_t)o4[o]*DTOT;
    }
    int lane = t & 63;
    int w = t >> 6;
    int tile0 = blockIdx.x * 32;
    const float* zl = z + lane;
    // zero accumulator tile
    for (int i=t; i<32*65; i+=256) A[i] = 0.f;
    __syncthreads();
    int eStart = __builtin_amdgcn_readfirstlane(row_ptr[tile0]);
    int eEnd   = __builtin_amdgcn_readfirstlane(row_ptr[tile0+32]);
    int total  = eEnd - eStart;
    int per    = (total + 3) >> 2;
    int we0 = eStart + w*per;
    int we1 = we0 + per; if (we1 > eEnd) we1 = eEnd; if (we0 > eEnd) we0 = eEnd;
    int e = we0;
    for (; e + 8 <= we1; e += 8){
        int2 p0 = s_edge[e+0], p1 = s_edge[e+1], p2 = s_edge[e+2], p3 = s_edge[e+3];
        int2 p4 = s_edge[e+4], p5 = s_edge[e+5], p6 = s_edge[e+6], p7 = s_edge[e+7];
        float z0 = zl[(p0.x & 0xFFFF)*HH];
        float z1 = zl[(p1.x & 0xFFFF)*HH];
        float z2 = zl[(p2.x & 0xFFFF)*HH];
        float z3 = zl[(p3.x & 0xFFFF)*HH];
        float z4 = zl[(p4.x & 0xFFFF)*HH];
        float z5 = zl[(p5.x & 0xFFFF)*HH];
        float z6 = zl[(p6.x & 0xFFFF)*HH];
        float z7 = zl[(p7.x & 0xFFFF)*HH];
        atomicAdd(&A[(p0.x >> 16)*65 + lane], __int_as_float(p0.y)*z0);
        atomicAdd(&A[(p1.x >> 16)*65 + lane], __int_as_float(p1.y)*z1);
        atomicAdd(&A[(p2.x >> 16)*65 + lane], __int_as_float(p2.y)*z2);
        atomicAdd(&A[(p3.x >> 16)*65 + lane], __int_as_float(p3.y)*z3);
        atomicAdd(&A[(p4.x >> 16)*65 + lane], __int_as_float(p4.y)*z4);
        atomicAdd(&A[(p5.x >> 16)*65 + lane], __int_as_float(p5.y)*z5);
        atomicAdd(&A[(p6.x >> 16)*65 + lane], __int_as_float(p6.y)*z6);
        atomicAdd(&A[(p7.x >> 16)*65 + lane], __int_as_float(p7.y)*z7);
    }
    for (; e < we1; ++e){
        int2 p = s_edge[e];
        float zv = zl[(p.x & 0xFFFF)*HH];
        atomicAdd(&A[(p.x >> 16)*65 + lane], __int_as_float(p.y)*zv);
    }
    __syncthreads();
    // phase B: out = agg @ WcT (thread: 2 nodes x 4 channels)
    int tn = t & 15;
    int tc = t >> 4;
    float c2[2][4];
    #pragma unroll
    for (int i=0;i<2;++i){
        #pragma unroll
        for (int j=0;j<4;++j) c2[i][j]=0.f;
    }
    #pragma unroll 4
    for (int k=0;k<64;++k){
        float4 b = *(const float4*)&WcT[k*64 + tc*4];
        #pragma unroll
        for (int i=0;i<2;++i){
            float a = A[(tn+16*i)*65 + k];
            c2[i][0] = fmaf(a, b.x, c2[i][0]);
            c2[i][1] = fmaf(a, b.y, c2[i][1]);
            c2[i][2] = fmaf(a, b.z, c2[i][2]);
            c2[i][3] = fmaf(a, b.w, c2[i][3]);
        }
    }
    float4 cbv = *(const float4*)&cb[tc*4];
    float p[NOTH+1];
    #pragma unroll
    for (int i=0;i<NOTH+1;++i) p[i]=0.f;
    float bnA[4] = {0.f,0.f,0.f,0.f};
    float bnB[4] = {0.f,0.f,0.f,0.f};
    #pragma unroll
    for (int i=0;i<2;++i){
        int n = tile0 + tn + 16*i;
        int base = n*HH + tc*4;
        float4 xi = *(const float4*)&xinj[base];
        float4 F4;
        F4.x = fmaxf(c2[i][0] + cbv.x + xi.x, 0.f);
        F4.y = fmaxf(c2[i][1] + cbv.y + xi.y, 0.f);
        F4.z = fmaxf(c2[i][2] + cbv.z + xi.z, 0.f);
        F4.w = fmaxf(c2[i][3] + cbv.w + xi.w, 0.f);
        *(float4*)&Fo[base] = F4;
        if constexpr (FINAL){
            bnA[0]+=F4.x; bnB[0]+=F4.x*F4.x;
            bnA[1]+=F4.y; bnB[1]+=F4.y*F4.y;
            bnA[2]+=F4.z; bnB[2]+=F4.z*F4.z;
            bnA[3]+=F4.w; bnB[3]+=F4.w*F4.w;
        } else {
            float4 z4 = *(const float4*)&z[base];
            float4 G4;
            G4.x = F4.x - z4.x; G4.y = F4.y - z4.y;
            G4.z = F4.z - z4.z; G4.w = F4.w - z4.w;
            *(float4*)&Go[base] = G4;
            p[NOTH] += G4.x*G4.x + G4.y*G4.y + G4.z*G4.z + G4.w*G4.w;
            #pragma unroll
            for (int o=0;o<NOTH;++o){
                float4 g4 = *(const float4*)&gop[o][base];
                p[o] += G4.x*g4.x + G4.y*g4.y + G4.z*g4.z + G4.w*g4.w;
            }
        }
    }
    if constexpr (FINAL){
        #pragma unroll
        for (int j=0;j<4;++j){
            #pragma unroll
            for (int off=8; off>0; off>>=1){
                bnA[j] += __shfl_down(bnA[j], off, 16);
                bnB[j] += __shfl_down(bnB[j], off, 16);
            }
        }
        __shared__ float bnredA[64], bnredB[64];
        if (tn==0){
            #pragma unroll
            for (int j=0;j<4;++j){ bnredA[tc*4+j]=bnA[j]; bnredB[tc*4+j]=bnB[j]; }
        }
        __syncthreads();
        if (t < 64){
            int cp = (blockIdx.x & 7) * HH;
            atomicAdd(&bn1[cp+t], bnredA[t]);
            atomicAdd(&bn2[cp+t], bnredB[t]);
        }
    } else {
        #pragma unroll
        for (int i=0;i<NOTH+1;++i){
            #pragma unroll
            for (int off=32; off>0; off>>=1) p[i] += __shfl_down(p[i], off, 64);
        }
        __shared__ float red[4][5];
        if (lane==0){
            #pragma unroll
            for (int i=0;i<NOTH+1;++i) red[w][i]=p[i];
        }
        __syncthreads();
        if (t < NOTH+1){
            float v = red[0][t]+red[1][t]+red[2][t]+red[3][t];
            int o4[4] = {oth.x, oth.y, oth.z, oth.w};
            int tgt = (t==NOTH) ? newSlot : o4[t];
            atomicAdd(&gram[newSlot*5 + tgt], v);
        }
    }
}

// ---------------- xnew with fused Anderson solve (per-block, registers) -------
__global__ __launch_bounds__(256) void xnew_kernel(const float* __restrict__ Fbase,
                            const float* __restrict__ gram,
                            int n, int w0, float* __restrict__ xnew){
    int sl[5];
    #pragma unroll
    for (int a=0;a<5;++a) sl[a] = (w0+a)%5;
    float A[5][5]; float rhs[5];
    #pragma unroll
    for (int a=0;a<5;++a){
        #pragma unroll
        for (int b=0;b<5;++b){
            float v;
            if (a<n && b<n){
                int wa = (a>b)?a:b;
                int wb = (a>b)?b:a;
                v = gram[sl[wa]*5 + sl[wb]];
            } else v = (a==b)?1.f:0.f;
            A[a][b] = v;
        }
        if (a<n) A[a][a] += 1e-4f;
        rhs[a] = (a<n)? 1.f : 0.f;
    }
    #pragma unroll
    for (int k=0;k<5;++k){
        float inv = 1.f/A[k][k];
        #pragma unroll
        for (int j=0;j<5;++j) A[k][j] *= inv;
        rhs[k] *= inv;
        #pragma unroll
        for (int i=0;i<5;++i){
            if (i==k) continue;
            float f = A[i][k];
            #pragma unroll
            for (int j=0;j<5;++j) A[i][j] -= f*A[k][j];
            rhs[i] -= f*rhs[k];
        }
    }
    float ssum = rhs[0]+rhs[1]+rhs[2]+rhs[3]+rhs[4];
    float invs = 1.f/ssum;
    float a0=rhs[0]*invs, a1=rhs[1]*invs, a2=rhs[2]*invs, a3=rhs[3]*invs, a4=rhs[4]*invs;

    int i = blockIdx.x*blockDim.x+threadIdx.x;
    if (i >= DTOT/4) return;
    const float4* F0 = (const float4*)(Fbase + (size_t)sl[0]*DTOT);
    const float4* F1 = (const float4*)(Fbase + (size_t)sl[1]*DTOT);
    const float4* F2 = (const float4*)(Fbase + (size_t)sl[2]*DTOT);
    const float4* F3 = (const float4*)(Fbase + (size_t)sl[3]*DTOT);
    const float4* F4 = (const float4*)(Fbase + (size_t)sl[4]*DTOT);
    float4 v = F0[i];
    float4 s = make_float4(a0*v.x, a0*v.y, a0*v.z, a0*v.w);
    v = F1[i]; s.x += a1*v.x; s.y += a1*v.y; s.z += a1*v.z; s.w += a1*v.w;
    if (n>2){ v = F2[i]; s.x += a2*v.x; s.y += a2*v.y; s.z += a2*v.z; s.w += a2*v.w; }
    if (n>3){ v = F3[i]; s.x += a3*v.x; s.y += a3*v.y; s.z += a3*v.z; s.w += a3*v.w; }
    if (n>4){ v = F4[i]; s.x += a4*v.x; s.y += a4*v.y; s.z += a4*v.z; s.w += a4*v.w; }
    ((float4*)xnew)[i] = s;
}

// ---------------- fused BN + segmented mean-pool + dec MLP (one block/graph) ---
__global__ __launch_bounds__(256) void pool_dec_kernel(
    const float* __restrict__ x, const int* __restrict__ gstart,
    const float* __restrict__ bn1, const float* __restrict__ bn2,
    const float* __restrict__ gamma, const float* __restrict__ beta,
    const float* __restrict__ W3, const float* __restrict__ b3,
    const float* __restrict__ W4, const float* __restrict__ b4,
    float* __restrict__ out)
{
    __shared__ float scs[HH], shs[HH];
    __shared__ float red[4][HH];
    __shared__ float pooled[HH];
    __shared__ float tv[HH];
    int g = blockIdx.x;
    int t = threadIdx.x;
    int lane = t & 63, w = t >> 6;
    if (t < HH){
        float a=0.f, b=0.f;
        #pragma unroll
        for (int c=0;c<8;++c){ a += bn1[c*HH+t]; b += bn2[c*HH+t]; }
        float mu  = a*(1.f/NN);
        float var = b*(1.f/NN) - mu*mu;
        float sc = gamma[t]*rsqrtf(var+1e-5f);
        scs[t]=sc; shs[t]=beta[t]-mu*sc;
    }
    __syncthreads();
    int n0 = gstart[g], n1 = gstart[g+1];
    float sc = scs[lane], sh = shs[lane];
    float acc = 0.f;
    for (int n = n0 + w; n < n1; n += 4)
        acc += fmaxf(x[n*HH+lane]*sc + sh, 0.f);
    red[w][lane] = acc;
    __syncthreads();
    if (t < HH){
        float s = red[0][t]+red[1][t]+red[2][t]+red[3][t];
        pooled[t] = s / fmaxf((float)(n1-n0), 1.f);
    }
    __syncthreads();
    if (t < HH){
        float a = b3[t];
        for (int k=0;k<HH;++k) a += pooled[k]*W3[k*HH+t];
        tv[t] = gelu_exact(a);
    }
    __syncthreads();
    if (t < OUTC){
        float o = b4[t];
        for (int c=0;c<HH;++c) o += tv[c]*W4[c*OUTC + t];
        out[g*OUTC + t] = o;
    }
}

// ---------------- host launch ----------------
static inline void launch_feval(int nOth, int fin, const float* z, const float* xinj, const float* WcT,
                                const float* cb, const int* row_ptr, const int2* s_edge,
                                float* Fo, float* Go, const float* Gbase, float* gram,
                                int newSlot, int4 oth, float* bn1, float* bn2, hipStream_t stream)
{
    if (fin){
        feval_kernel<0,1><<<NN/32,256,0,stream>>>(z,xinj,WcT,cb,row_ptr,s_edge,Fo,Go,Gbase,gram,newSlot,oth,bn1,bn2);
        return;
    }
    switch (nOth){
    case 1: feval_kernel<1,0><<<NN/32,256,0,stream>>>(z,xinj,WcT,cb,row_ptr,s_edge,Fo,Go,Gbase,gram,newSlot,oth,bn1,bn2); break;
    case 2: feval_kernel<2,0><<<NN/32,256,0,stream>>>(z,xinj,WcT,cb,row_ptr,s_edge,Fo,Go,Gbase,gram,newSlot,oth,bn1,bn2); break;
    case 3: feval_kernel<3,0><<<NN/32,256,0,stream>>>(z,xinj,WcT,cb,row_ptr,s_edge,Fo,Go,Gbase,gram,newSlot,oth,bn1,bn2); break;
    default: feval_kernel<4,0><<<NN/32,256,0,stream>>>(z,xinj,WcT,cb,row_ptr,s_edge,Fo,Go,Gbase,gram,newSlot,oth,bn1,bn2); break;
    }
}

extern "C" void kernel_launch(void* const* d_in, const int* in_sizes, int n_in,
                              void* d_out, int out_size, void* d_ws, size_t ws_size,
                              hipStream_t stream)
{
    const int*   dx    = (const int*)d_in[0];
    const int*   ei    = (const int*)d_in[1];
    const float* ew    = (const float*)d_in[2];
    const int*   batch = (const int*)d_in[3];
    const float* emb   = (const float*)d_in[4];
    const float* W1    = (const float*)d_in[5];
    const float* b1    = (const float*)d_in[6];
    const float* W2    = (const float*)d_in[7];
    const float* b2    = (const float*)d_in[8];
    const float* M     = (const float*)d_in[9];
    const float* cb    = (const float*)d_in[10];
    const float* bng   = (const float*)d_in[11];
    const float* bnb   = (const float*)d_in[12];
    const float* W3    = (const float*)d_in[13];
    const float* b3    = (const float*)d_in[14];
    const float* W4    = (const float*)d_in[15];
    const float* b4    = (const float*)d_in[16];
    float* out = (float*)d_out;

    char* wsbase = (char*)d_ws;
    size_t off = 0;
    auto alloc = [&](size_t bytes)->char*{
        char* p = wsbase + off;
        off += (bytes + 255) / 256 * 256;
        return p;
    };
    float* xinj  = (float*)alloc((size_t)DTOT*4);
    float* Fring = (float*)alloc(5*(size_t)DTOT*4);
    float* Gring = (float*)alloc(5*(size_t)DTOT*4);
    float* xbuf  = (float*)alloc((size_t)DTOT*4);
    float* WcT   = (float*)alloc(HH*HH*4);
    float* gram  = (float*)alloc(25*4);
    float* bnbuf = (float*)alloc(2*8*HH*4);     // bn1[8][64], bn2[8][64]
    int*  gstart = (int*)alloc((size_t)(GGG+1)*4);
    int*  counts = (int*)alloc((size_t)NN*4);
    int*  row_ptr= (int*)alloc((size_t)(NN+1)*4);
    int*  cursor = (int*)alloc((size_t)NN*4);
    int2* s_edge = (int2*)alloc((size_t)EE*8);
    float* bn1 = bnbuf;
    float* bn2 = bnbuf + 8*HH;
    (void)ws_size; (void)in_sizes; (void)n_in; (void)out_size;

    // merged setup: cayley(b0) + gbound(b1) + enc + hist
    hipMemsetAsync(counts, 0, (size_t)NN*4, stream);
    setup_kernel<<<2 + ENC_BLOCKS + HIST_BLOCKS, 256, 0, stream>>>(
        dx, emb, W1,b1,W2,b2, xinj, M, WcT, batch, gstart, ei, counts);
    scan_kernel<<<1,1024,0,stream>>>(counts, row_ptr, cursor);
    fill_kernel<<<EE/256,256,0,stream>>>(ei, ew, cursor, s_edge);

    // Anderson
    hipMemsetAsync(gram, 0, 25*4, stream);
    hipMemsetAsync(bnbuf, 0, 2*8*HH*4, stream);
    feval0_kernel<<<1024,256,0,stream>>>(xinj, cb, Fring, Gring, gram);
    {
        int4 oth = make_int4(0,0,0,0);
        launch_feval(1, 0, Fring, xinj, WcT, cb, row_ptr, s_edge,
                     Fring+(size_t)DTOT, Gring+(size_t)DTOT, Gring, gram, 1, oth, bn1, bn2, stream);
    }
    for (int k=2;k<10;++k){
        int n  = (k<5)?k:5;
        int w0 = k-n;
        int slot = k%5;
        // xnew reads gram (incl. the oldest-window row) BEFORE the evicted row is zeroed
        xnew_kernel<<<(DTOT/4+255)/256,256,0,stream>>>(Fring, gram, n, w0, xbuf);
        hipMemsetAsync(gram + slot*5, 0, 5*4, stream);   // zero row the next feval fills
        int nOth = (k<4)?k:4;
        int o4[4] = {0,0,0,0};
        for (int j=1;j<=nOth;++j) o4[j-1] = ((k-j)%5+5)%5;
        int4 oth = make_int4(o4[0],o4[1],o4[2],o4[3]);
        launch_feval(nOth, (k==9)?1:0, xbuf, xinj, WcT, cb, row_ptr, s_edge,
                     Fring+(size_t)slot*DTOT, Gring+(size_t)slot*DTOT, Gring, gram, slot, oth, bn1, bn2, stream);
    }
    float* zstar = Fring + (size_t)(9%5)*DTOT;

    // fused BN + pool + dec
    pool_dec_kernel<<<GGG,256,0,stream>>>(zstar, gstart, bn1, bn2, bng, bnb, W3,b3,W4,b4, out);
}

// Round 16
// 961.584 us; speedup vs baseline: 2.2128x; 2.2128x over previous
//
#include <hip/hip_runtime.h>
#include <math.h>

#define HH   64
#define NN   65536
#define EE   524288
#define GGG  256
#define OUTC 128
#define NFF  9
#define VV   128
#define DTOT (NN*HH)
#define ENC_BLOCKS (NN/64)
#define HIST_BLOCKS (EE/256)

__device__ __forceinline__ float gelu_exact(float x){
    return 0.5f * x * (1.0f + erff(x * 0.70710678118654752f));
}

// ---------------- merged setup: cayley(b0) + gbound(b1) + enc(b2..) + hist ----
// 16.6 KB static LDS for ALL roles -> 9 blocks/CU.
__global__ __launch_bounds__(256) void setup_kernel(
    const int* __restrict__ dx, const float* __restrict__ emb,
    const float* __restrict__ W1, const float* __restrict__ b1,
    const float* __restrict__ W2, const float* __restrict__ b2,
    float* __restrict__ xinj,
    const float* __restrict__ M, float* __restrict__ WcT,
    const int* __restrict__ batch, int* __restrict__ gstart,
    const int* __restrict__ ei, int* __restrict__ counts)
{
    __shared__ float smem[64*65];     // enc A-tile OR cayley in-place inverse
    int b = blockIdx.x;
    int t = threadIdx.x;
    if (b == 0){
        // ---- Cayley: in-place GJ inversion of A = I+S in [64][65] LDS.
        // Wc = 2*(I+S)^-1 - I. Thread owns col c (0..63) x rows h*16..h*16+15.
        float* A = smem;
        int c = t & 63;
        int h = t >> 6;               // 0..3
        for (int idx = t; idx < 64*64; idx += 256){
            int i = idx >> 6, j = idx & 63;
            float s = 0.5f*(M[i*HH+j] - M[j*HH+i]);
            A[i*65 + j] = ((i==j)?1.f:0.f) + s;
        }
        __syncthreads();
        for (int k=0;k<64;++k){
            float piv    = A[k*65 + k];
            float rowk_c = A[k*65 + c];
            float fc[16];
            #pragma unroll
            for (int r=0;r<16;++r) fc[r] = A[(h*16+r)*65 + k];
            __syncthreads();
            float pinv = 1.f/piv;
            float rowk_s = rowk_c * pinv;
            #pragma unroll
            for (int r=0;r<16;++r){
                int i = h*16 + r;
                float nv;
                if (i == k) nv = (c==k) ? pinv : rowk_s;
                else        nv = (c==k) ? (-fc[r]*pinv) : fmaf(-fc[r], rowk_s, A[i*65+c]);
                A[i*65+c] = nv;
            }
            __syncthreads();
        }
        // A[i][c] = Ainv[i][c]; WcT[k*64+c] = Wc[c][k] = 2*Ainv[c][k] - (k==c)
        for (int idx=t; idx<64*64; idx+=256){
            int k = idx >> 6, cc = idx & 63;
            WcT[k*HH+cc] = 2.f*A[cc*65 + k] - ((k==cc)?1.f:0.f);
        }
    } else if (b == 1){
        int g = t;
        int lo = 0, hi = NN;
        while (lo < hi){ int mid = (lo+hi)>>1; if (batch[mid] < g) lo = mid+1; else hi = mid; }
        gstart[g] = lo;
        if (g == 0) gstart[GGG] = NN;
    } else if (b < 2 + ENC_BLOCKS){
        // ---- enc: AtomEncoder + MLP, 64-node tile; W1/W2 read from global (L2)
        float* A = smem;              // [64][65]
        int lane = t & 63;
        int w = t >> 6;
        int tile0 = (b-2) * 64;
        for (int j=0;j<16;++j){
            int nl = w*16 + j;
            int n = tile0 + nl;
            float hsum = 0.f;
            #pragma unroll
            for (int f=0; f<NFF; ++f){
                int idx = dx[n*NFF+f];
                hsum += emb[(f*VV + idx)*HH + lane];
            }
            A[nl*65 + lane] = fmaxf(hsum, 0.f);
        }
        __syncthreads();
        int tn = t & 15;
        int tc = t >> 4;
        float c4[4][4];
        #pragma unroll
        for (int i=0;i<4;++i){
            #pragma unroll
            for (int j=0;j<4;++j) c4[i][j]=0.f;
        }
        #pragma unroll 4
        for (int k=0;k<64;++k){
            float4 bb = *(const float4*)&W1[k*64 + tc*4];
            #pragma unroll
            for (int i=0;i<4;++i){
                float a = A[(tn+16*i)*65 + k];
                c4[i][0] = fmaf(a, bb.x, c4[i][0]);
                c4[i][1] = fmaf(a, bb.y, c4[i][1]);
                c4[i][2] = fmaf(a, bb.z, c4[i][2]);
                c4[i][3] = fmaf(a, bb.w, c4[i][3]);
            }
        }
        float4 b1v = *(const float4*)&b1[tc*4];
        float b1a[4] = {b1v.x, b1v.y, b1v.z, b1v.w};
        __syncthreads();
        #pragma unroll
        for (int i=0;i<4;++i){
            #pragma unroll
            for (int j=0;j<4;++j)
                A[(tn+16*i)*65 + tc*4+j] = gelu_exact(c4[i][j] + b1a[j]);
        }
        __syncthreads();
        #pragma unroll
        for (int i=0;i<4;++i){
            #pragma unroll
            for (int j=0;j<4;++j) c4[i][j]=0.f;
        }
        #pragma unroll 4
        for (int k=0;k<64;++k){
            float4 bb = *(const float4*)&W2[k*64 + tc*4];
            #pragma unroll
            for (int i=0;i<4;++i){
                float a = A[(tn+16*i)*65 + k];
                c4[i][0] = fmaf(a, bb.x, c4[i][0]);
                c4[i][1] = fmaf(a, bb.y, c4[i][1]);
                c4[i][2] = fmaf(a, bb.z, c4[i][2]);
                c4[i][3] = fmaf(a, bb.w, c4[i][3]);
            }
        }
        float4 b2v = *(const float4*)&b2[tc*4];
        #pragma unroll
        for (int i=0;i<4;++i){
            int n = tile0 + tn + 16*i;
            float4 o4;
            o4.x = c4[i][0] + b2v.x;
            o4.y = c4[i][1] + b2v.y;
            o4.z = c4[i][2] + b2v.z;
            o4.w = c4[i][3] + b2v.w;
            *(float4*)&xinj[n*HH + tc*4] = o4;
        }
    } else {
        int e = (b - 2 - ENC_BLOCKS)*256 + t;
        if (e < EE) atomicAdd(&counts[ei[EE + e]], 1);
    }
}

// ---------------- CSR scan + fill ----------------
__global__ __launch_bounds__(1024) void scan_kernel(const int* __restrict__ counts, int* __restrict__ row_ptr, int* __restrict__ cursor){
    __shared__ int lds[1024];
    int t = threadIdx.x;
    int base = t*64;
    int s=0;
    for (int i=0;i<64;++i) s += counts[base+i];
    lds[t]=s; __syncthreads();
    if (t==0){ int run=0; for (int i=0;i<1024;++i){ int v=lds[i]; lds[i]=run; run+=v; } }
    __syncthreads();
    int run = lds[t];
    for (int i=0;i<64;++i){ row_ptr[base+i]=run; cursor[base+i]=run; run += counts[base+i]; }
    if (t==1023) row_ptr[NN]=run;
}

// pack: x = src (low 16 bits; src < 65536 fits exactly), w in y
__global__ void fill_kernel(const int* __restrict__ ei, const float* __restrict__ ew,
                            int* __restrict__ cursor, int2* __restrict__ s_edge){
    int e = blockIdx.x*blockDim.x + threadIdx.x;
    if (e < EE){
        int dstn = ei[EE+e];
        int pos = atomicAdd(&cursor[dstn], 1);
        s_edge[pos] = make_int2(ei[e] & 0xFFFF, __float_as_int(ew[e]));
    }
}

// ---------------- f evaluations ----------------
__global__ __launch_bounds__(256) void feval0_kernel(const float* __restrict__ xinj, const float* __restrict__ cb,
                              float* __restrict__ F0, float* __restrict__ G0, float* __restrict__ gram){
    float ps = 0.f;
    int stride = gridDim.x*blockDim.x;
    for (int i = blockIdx.x*blockDim.x + threadIdx.x; i < DTOT; i += stride){
        float v = fmaxf(cb[i&63] + xinj[i], 0.f);
        F0[i]=v; G0[i]=v; ps += v*v;
    }
    #pragma unroll
    for (int off=32; off>0; off>>=1) ps += __shfl_down(ps, off, 64);
    __shared__ float red[4];
    int lane = threadIdx.x&63, w = threadIdx.x>>6;
    if (lane==0) red[w]=ps;
    __syncthreads();
    if (threadIdx.x==0) atomicAdd(&gram[0], red[0]+red[1]+red[2]+red[3]);
}

// F = relu(Wc @ agg(z) + cb + xinj). 32-node tile / block.
// Per-node gather (verified fast): packed int2 edges, unroll 8 -> 4 -> 1,
// readfirstlane'd bounds -> scalar edge loads, 8 z-rows in flight.
template<int NOTH, int FINAL>
__global__ __launch_bounds__(256) void feval_kernel(
    const float* __restrict__ z, const float* __restrict__ xinj,
    const float* __restrict__ WcT, const float* __restrict__ cb,
    const int* __restrict__ row_ptr, const int2* __restrict__ s_edge,
    float* __restrict__ Fo, float* __restrict__ Go,
    const float* __restrict__ Gbase, float* __restrict__ gram, int newSlot, int4 oth,
    float* __restrict__ bn1, float* __restrict__ bn2)
{
    __shared__ float A[32*65];
    int t = threadIdx.x;
    const float* gop[4];
    {
        int o4[4] = {oth.x, oth.y, oth.z, oth.w};
        #pragma unroll
        for (int o=0;o<4;++o) gop[o] = Gbase + (size_t)o4[o]*DTOT;
    }
    int lane = t & 63;
    int w = t >> 6;
    int tile0 = blockIdx.x * 32;
    const float* zl = z + lane;
    // phase A: sparse gather, 8 nodes per wave, lane = channel
    for (int j=0;j<8;++j){
        int nl = w*8 + j;
        int n = tile0 + nl;
        int e0 = __builtin_amdgcn_readfirstlane(row_ptr[n]);
        int e1 = __builtin_amdgcn_readfirstlane(row_ptr[n+1]);
        float acc = 0.f;
        int e = e0;
        for (; e + 8 <= e1; e += 8){
            int2 p0 = s_edge[e+0], p1 = s_edge[e+1], p2 = s_edge[e+2], p3 = s_edge[e+3];
            int2 p4 = s_edge[e+4], p5 = s_edge[e+5], p6 = s_edge[e+6], p7 = s_edge[e+7];
            float z0 = zl[(p0.x & 0xFFFF)*HH];
            float z1 = zl[(p1.x & 0xFFFF)*HH];
            float z2 = zl[(p2.x & 0xFFFF)*HH];
            float z3 = zl[(p3.x & 0xFFFF)*HH];
            float z4 = zl[(p4.x & 0xFFFF)*HH];
            float z5 = zl[(p5.x & 0xFFFF)*HH];
            float z6 = zl[(p6.x & 0xFFFF)*HH];
            float z7 = zl[(p7.x & 0xFFFF)*HH];
            acc = fmaf(__int_as_float(p0.y), z0, acc);
            acc = fmaf(__int_as_float(p1.y), z1, acc);
            acc = fmaf(__int_as_float(p2.y), z2, acc);
            acc = fmaf(__int_as_float(p3.y), z3, acc);
            acc = fmaf(__int_as_float(p4.y), z4, acc);
            acc = fmaf(__int_as_float(p5.y), z5, acc);
            acc = fmaf(__int_as_float(p6.y), z6, acc);
            acc = fmaf(__int_as_float(p7.y), z7, acc);
        }
        for (; e + 4 <= e1; e += 4){
            int2 p0 = s_edge[e+0], p1 = s_edge[e+1], p2 = s_edge[e+2], p3 = s_edge[e+3];
            float z0 = zl[(p0.x & 0xFFFF)*HH];
            float z1 = zl[(p1.x & 0xFFFF)*HH];
            float z2 = zl[(p2.x & 0xFFFF)*HH];
            float z3 = zl[(p3.x & 0xFFFF)*HH];
            acc = fmaf(__int_as_float(p0.y), z0, acc);
            acc = fmaf(__int_as_float(p1.y), z1, acc);
            acc = fmaf(__int_as_float(p2.y), z2, acc);
            acc = fmaf(__int_as_float(p3.y), z3, acc);
        }
        for (; e < e1; ++e){
            int2 p = s_edge[e];
            acc = fmaf(__int_as_float(p.y), zl[(p.x & 0xFFFF)*HH], acc);
        }
        A[nl*65 + lane] = acc;
    }
    __syncthreads();
    // phase B: out = agg @ WcT (thread: 2 nodes x 4 channels)
    int tn = t & 15;
    int tc = t >> 4;
    float c2[2][4];
    #pragma unroll
    for (int i=0;i<2;++i){
        #pragma unroll
        for (int j=0;j<4;++j) c2[i][j]=0.f;
    }
    #pragma unroll 4
    for (int k=0;k<64;++k){
        float4 b = *(const float4*)&WcT[k*64 + tc*4];
        #pragma unroll
        for (int i=0;i<2;++i){
            float a = A[(tn+16*i)*65 + k];
            c2[i][0] = fmaf(a, b.x, c2[i][0]);
            c2[i][1] = fmaf(a, b.y, c2[i][1]);
            c2[i][2] = fmaf(a, b.z, c2[i][2]);
            c2[i][3] = fmaf(a, b.w, c2[i][3]);
        }
    }
    float4 cbv = *(const float4*)&cb[tc*4];
    float p[NOTH+1];
    #pragma unroll
    for (int i=0;i<NOTH+1;++i) p[i]=0.f;
    float bnA[4] = {0.f,0.f,0.f,0.f};
    float bnB[4] = {0.f,0.f,0.f,0.f};
    #pragma unroll
    for (int i=0;i<2;++i){
        int n = tile0 + tn + 16*i;
        int base = n*HH + tc*4;
        float4 xi = *(const float4*)&xinj[base];
        float4 F4;
        F4.x = fmaxf(c2[i][0] + cbv.x + xi.x, 0.f);
        F4.y = fmaxf(c2[i][1] + cbv.y + xi.y, 0.f);
        F4.z = fmaxf(c2[i][2] + cbv.z + xi.z, 0.f);
        F4.w = fmaxf(c2[i][3] + cbv.w + xi.w, 0.f);
        *(float4*)&Fo[base] = F4;
        if constexpr (FINAL){
            bnA[0]+=F4.x; bnB[0]+=F4.x*F4.x;
            bnA[1]+=F4.y; bnB[1]+=F4.y*F4.y;
            bnA[2]+=F4.z; bnB[2]+=F4.z*F4.z;
            bnA[3]+=F4.w; bnB[3]+=F4.w*F4.w;
        } else {
            float4 z4 = *(const float4*)&z[base];
            float4 G4;
            G4.x = F4.x - z4.x; G4.y = F4.y - z4.y;
            G4.z = F4.z - z4.z; G4.w = F4.w - z4.w;
            *(float4*)&Go[base] = G4;
            p[NOTH] += G4.x*G4.x + G4.y*G4.y + G4.z*G4.z + G4.w*G4.w;
            #pragma unroll
            for (int o=0;o<NOTH;++o){
                float4 g4 = *(const float4*)&gop[o][base];
                p[o] += G4.x*g4.x + G4.y*g4.y + G4.z*g4.z + G4.w*g4.w;
            }
        }
    }
    if constexpr (FINAL){
        #pragma unroll
        for (int j=0;j<4;++j){
            #pragma unroll
            for (int off=8; off>0; off>>=1){
                bnA[j] += __shfl_down(bnA[j], off, 16);
                bnB[j] += __shfl_down(bnB[j], off, 16);
            }
        }
        __shared__ float bnredA[64], bnredB[64];
        if (tn==0){
            #pragma unroll
            for (int j=0;j<4;++j){ bnredA[tc*4+j]=bnA[j]; bnredB[tc*4+j]=bnB[j]; }
        }
        __syncthreads();
        if (t < 64){
            int cp = (blockIdx.x & 7) * HH;
            atomicAdd(&bn1[cp+t], bnredA[t]);
            atomicAdd(&bn2[cp+t], bnredB[t]);
        }
    } else {
        #pragma unroll
        for (int i=0;i<NOTH+1;++i){
            #pragma unroll
            for (int off=32; off>0; off>>=1) p[i] += __shfl_down(p[i], off, 64);
        }
        __shared__ float red[4][5];
        if (lane==0){
            #pragma unroll
            for (int i=0;i<NOTH+1;++i) red[w][i]=p[i];
        }
        __syncthreads();
        if (t < NOTH+1){
            float v = red[0][t]+red[1][t]+red[2][t]+red[3][t];
            int o4[4] = {oth.x, oth.y, oth.z, oth.w};
            int tgt = (t==NOTH) ? newSlot : o4[t];
            atomicAdd(&gram[newSlot*5 + tgt], v);
        }
    }
}

// ---------------- xnew with fused Anderson solve (per-block, registers) -------
__global__ __launch_bounds__(256) void xnew_kernel(const float* __restrict__ Fbase,
                            const float* __restrict__ gram,
                            int n, int w0, float* __restrict__ xnew){
    int sl[5];
    #pragma unroll
    for (int a=0;a<5;++a) sl[a] = (w0+a)%5;
    float A[5][5]; float rhs[5];
    #pragma unroll
    for (int a=0;a<5;++a){
        #pragma unroll
        for (int b=0;b<5;++b){
            float v;
            if (a<n && b<n){
                int wa = (a>b)?a:b;
                int wb = (a>b)?b:a;
                v = gram[sl[wa]*5 + sl[wb]];
            } else v = (a==b)?1.f:0.f;
            A[a][b] = v;
        }
        if (a<n) A[a][a] += 1e-4f;
        rhs[a] = (a<n)? 1.f : 0.f;
    }
    #pragma unroll
    for (int k=0;k<5;++k){
        float inv = 1.f/A[k][k];
        #pragma unroll
        for (int j=0;j<5;++j) A[k][j] *= inv;
        rhs[k] *= inv;
        #pragma unroll
        for (int i=0;i<5;++i){
            if (i==k) continue;
            float f = A[i][k];
            #pragma unroll
            for (int j=0;j<5;++j) A[i][j] -= f*A[k][j];
            rhs[i] -= f*rhs[k];
        }
    }
    float ssum = rhs[0]+rhs[1]+rhs[2]+rhs[3]+rhs[4];
    float invs = 1.f/ssum;
    float a0=rhs[0]*invs, a1=rhs[1]*invs, a2=rhs[2]*invs, a3=rhs[3]*invs, a4=rhs[4]*invs;

    int i = blockIdx.x*blockDim.x+threadIdx.x;
    if (i >= DTOT/4) return;
    const float4* F0 = (const float4*)(Fbase + (size_t)sl[0]*DTOT);
    const float4* F1 = (const float4*)(Fbase + (size_t)sl[1]*DTOT);
    const float4* F2 = (const float4*)(Fbase + (size_t)sl[2]*DTOT);
    const float4* F3 = (const float4*)(Fbase + (size_t)sl[3]*DTOT);
    const float4* F4 = (const float4*)(Fbase + (size_t)sl[4]*DTOT);
    float4 v = F0[i];
    float4 s = make_float4(a0*v.x, a0*v.y, a0*v.z, a0*v.w);
    v = F1[i]; s.x += a1*v.x; s.y += a1*v.y; s.z += a1*v.z; s.w += a1*v.w;
    if (n>2){ v = F2[i]; s.x += a2*v.x; s.y += a2*v.y; s.z += a2*v.z; s.w += a2*v.w; }
    if (n>3){ v = F3[i]; s.x += a3*v.x; s.y += a3*v.y; s.z += a3*v.z; s.w += a3*v.w; }
    if (n>4){ v = F4[i]; s.x += a4*v.x; s.y += a4*v.y; s.z += a4*v.z; s.w += a4*v.w; }
    ((float4*)xnew)[i] = s;
}

// ---------------- fused BN + segmented mean-pool + dec MLP (one block/graph) ---
__global__ __launch_bounds__(256) void pool_dec_kernel(
    const float* __restrict__ x, const int* __restrict__ gstart,
    const float* __restrict__ bn1, const float* __restrict__ bn2,
    const float* __restrict__ gamma, const float* __restrict__ beta,
    const float* __restrict__ W3, const float* __restrict__ b3,
    const float* __restrict__ W4, const float* __restrict__ b4,
    float* __restrict__ out)
{
    __shared__ float scs[HH], shs[HH];
    __shared__ float red[4][HH];
    __shared__ float pooled[HH];
    __shared__ float tv[HH];
    int g = blockIdx.x;
    int t = threadIdx.x;
    int lane = t & 63, w = t >> 6;
    if (t < HH){
        float a=0.f, b=0.f;
        #pragma unroll
        for (int c=0;c<8;++c){ a += bn1[c*HH+t]; b += bn2[c*HH+t]; }
        float mu  = a*(1.f/NN);
        float var = b*(1.f/NN) - mu*mu;
        float sc = gamma[t]*rsqrtf(var+1e-5f);
        scs[t]=sc; shs[t]=beta[t]-mu*sc;
    }
    __syncthreads();
    int n0 = gstart[g], n1 = gstart[g+1];
    float sc = scs[lane], sh = shs[lane];
    float acc = 0.f;
    for (int n = n0 + w; n < n1; n += 4)
        acc += fmaxf(x[n*HH+lane]*sc + sh, 0.f);
    red[w][lane] = acc;
    __syncthreads();
    if (t < HH){
        float s = red[0][t]+red[1][t]+red[2][t]+red[3][t];
        pooled[t] = s / fmaxf((float)(n1-n0), 1.f);
    }
    __syncthreads();
    if (t < HH){
        float a = b3[t];
        for (int k=0;k<HH;++k) a += pooled[k]*W3[k*HH+t];
        tv[t] = gelu_exact(a);
    }
    __syncthreads();
    if (t < OUTC){
        float o = b4[t];
        for (int c=0;c<HH;++c) o += tv[c]*W4[c*OUTC + t];
        out[g*OUTC + t] = o;
    }
}

// ---------------- host launch ----------------
static inline void launch_feval(int nOth, int fin, const float* z, const float* xinj, const float* WcT,
                                const float* cb, const int* row_ptr, const int2* s_edge,
                                float* Fo, float* Go, const float* Gbase, float* gram,
                                int newSlot, int4 oth, float* bn1, float* bn2, hipStream_t stream)
{
    if (fin){
        feval_kernel<0,1><<<NN/32,256,0,stream>>>(z,xinj,WcT,cb,row_ptr,s_edge,Fo,Go,Gbase,gram,newSlot,oth,bn1,bn2);
        return;
    }
    switch (nOth){
    case 1: feval_kernel<1,0><<<NN/32,256,0,stream>>>(z,xinj,WcT,cb,row_ptr,s_edge,Fo,Go,Gbase,gram,newSlot,oth,bn1,bn2); break;
    case 2: feval_kernel<2,0><<<NN/32,256,0,stream>>>(z,xinj,WcT,cb,row_ptr,s_edge,Fo,Go,Gbase,gram,newSlot,oth,bn1,bn2); break;
    case 3: feval_kernel<3,0><<<NN/32,256,0,stream>>>(z,xinj,WcT,cb,row_ptr,s_edge,Fo,Go,Gbase,gram,newSlot,oth,bn1,bn2); break;
    default: feval_kernel<4,0><<<NN/32,256,0,stream>>>(z,xinj,WcT,cb,row_ptr,s_edge,Fo,Go,Gbase,gram,newSlot,oth,bn1,bn2); break;
    }
}

extern "C" void kernel_launch(void* const* d_in, const int* in_sizes, int n_in,
                              void* d_out, int out_size, void* d_ws, size_t ws_size,
                              hipStream_t stream)
{
    const int*   dx    = (const int*)d_in[0];
    const int*   ei    = (const int*)d_in[1];
    const float* ew    = (const float*)d_in[2];
    const int*   batch = (const int*)d_in[3];
    const float* emb   = (const float*)d_in[4];
    const float* W1    = (const float*)d_in[5];
    const float* b1    = (const float*)d_in[6];
    const float* W2    = (const float*)d_in[7];
    const float* b2    = (const float*)d_in[8];
    const float* M     = (const float*)d_in[9];
    const float* cb    = (const float*)d_in[10];
    const float* bng   = (const float*)d_in[11];
    const float* bnb   = (const float*)d_in[12];
    const float* W3    = (const float*)d_in[13];
    const float* b3    = (const float*)d_in[14];
    const float* W4    = (const float*)d_in[15];
    const float* b4    = (const float*)d_in[16];
    float* out = (float*)d_out;

    char* wsbase = (char*)d_ws;
    size_t off = 0;
    auto alloc = [&](size_t bytes)->char*{
        char* p = wsbase + off;
        off += (bytes + 255) / 256 * 256;
        return p;
    };
    float* xinj  = (float*)alloc((size_t)DTOT*4);
    float* Fring = (float*)alloc(5*(size_t)DTOT*4);
    float* Gring = (float*)alloc(5*(size_t)DTOT*4);
    float* xbuf  = (float*)alloc((size_t)DTOT*4);
    float* WcT   = (float*)alloc(HH*HH*4);
    float* gram  = (float*)alloc(25*4);
    float* bnbuf = (float*)alloc(2*8*HH*4);     // bn1[8][64], bn2[8][64]
    int*  gstart = (int*)alloc((size_t)(GGG+1)*4);
    int*  counts = (int*)alloc((size_t)NN*4);
    int*  row_ptr= (int*)alloc((size_t)(NN+1)*4);
    int*  cursor = (int*)alloc((size_t)NN*4);
    int2* s_edge = (int2*)alloc((size_t)EE*8);
    float* bn1 = bnbuf;
    float* bn2 = bnbuf + 8*HH;
    (void)ws_size; (void)in_sizes; (void)n_in; (void)out_size;

    // merged setup: cayley(b0) + gbound(b1) + enc + hist
    hipMemsetAsync(counts, 0, (size_t)NN*4, stream);
    setup_kernel<<<2 + ENC_BLOCKS + HIST_BLOCKS, 256, 0, stream>>>(
        dx, emb, W1,b1,W2,b2, xinj, M, WcT, batch, gstart, ei, counts);
    scan_kernel<<<1,1024,0,stream>>>(counts, row_ptr, cursor);
    fill_kernel<<<EE/256,256,0,stream>>>(ei, ew, cursor, s_edge);

    // Anderson
    hipMemsetAsync(gram, 0, 25*4, stream);
    hipMemsetAsync(bnbuf, 0, 2*8*HH*4, stream);
    feval0_kernel<<<1024,256,0,stream>>>(xinj, cb, Fring, Gring, gram);
    {
        int4 oth = make_int4(0,0,0,0);
        launch_feval(1, 0, Fring, xinj, WcT, cb, row_ptr, s_edge,
                     Fring+(size_t)DTOT, Gring+(size_t)DTOT, Gring, gram, 1, oth, bn1, bn2, stream);
    }
    for (int k=2;k<10;++k){
        int n  = (k<5)?k:5;
        int w0 = k-n;
        int slot = k%5;
        // xnew reads gram (incl. the oldest-window row) BEFORE the evicted row is zeroed
        xnew_kernel<<<(DTOT/4+255)/256,256,0,stream>>>(Fring, gram, n, w0, xbuf);
        hipMemsetAsync(gram + slot*5, 0, 5*4, stream);   // zero row the next feval fills
        int nOth = (k<4)?k:4;
        int o4[4] = {0,0,0,0};
        for (int j=1;j<=nOth;++j) o4[j-1] = ((k-j)%5+5)%5;
        int4 oth = make_int4(o4[0],o4[1],o4[2],o4[3]);
        launch_feval(nOth, (k==9)?1:0, xbuf, xinj, WcT, cb, row_ptr, s_edge,
                     Fring+(size_t)slot*DTOT, Gring+(size_t)slot*DTOT, Gring, gram, slot, oth, bn1, bn2, stream);
    }
    float* zstar = Fring + (size_t)(9%5)*DTOT;

    // fused BN + pool + dec
    pool_dec_kernel<<<GGG,256,0,stream>>>(zstar, gstart, bn1, bn2, bng, bnb, W3,b3,W4,b4, out);
}